// Round 5
// baseline (71.998 us; speedup 1.0000x reference)
//
#include <hip/hip_runtime.h>

#define NELEC 64
#define NDIM 3
#define BPB 4                 // batches per block (1 wave = 1 batch)
#define BLOCK (BPB * NELEC)   // 256 threads

#if defined(__has_builtin)
#if __has_builtin(__builtin_amdgcn_rsqf)
#define RSQ(x) __builtin_amdgcn_rsqf(x)
#endif
#endif
#ifndef RSQ
#define RSQ(x) rsqrtf(x)
#endif

__global__ __launch_bounds__(BLOCK) void backflow_kernel(
    const float* __restrict__ pos, const float* __restrict__ w,
    float* __restrict__ out, int B)
{
    // Padded float4 per electron: each inner-loop read is one ds_read_b128
    // with a compile-time immediate offset; address is wave-uniform -> LDS
    // broadcast path, zero bank conflicts, overlaps the VALU pipe.
    __shared__ float4 smem[BPB * NELEC];

    const int t  = threadIdx.x;
    const int lb = t >> 6;    // wave id == local batch
    const int i  = t & 63;    // electron index
    const int b  = blockIdx.x * BPB + lb;
    const bool live = (b < B);   // B % BPB == 0 on the bench shape

    float rx = 0.f, ry = 0.f, rz = 0.f;
    if (live) {
        // per-lane 12B load: wave covers 768 contiguous bytes (coalesced)
        const float* p = pos + b * (NELEC * NDIM) + i * NDIM;
        rx = p[0]; ry = p[1]; rz = p[2];
        smem[t] = make_float4(rx, ry, rz, 0.f);   // one ds_write_b128
    }
    __syncthreads();

    if (live) {
        const float wv = w[0];                    // wave-uniform
        const float4* rb = &smem[lb * NELEC];

        // split accumulators: halves the serial fma chain (ILP insurance)
        float ax0 = 0.f, ay0 = 0.f, az0 = 0.f;
        float ax1 = 0.f, ay1 = 0.f, az1 = 0.f;

        #pragma unroll
        for (int j = 0; j < NELEC; j += 2) {
            float4 rja = rb[j];                   // broadcast ds_read_b128
            float4 rjb = rb[j + 1];
            float dxa = rx - rja.x, dya = ry - rja.y, dza = rz - rja.z;
            float dxb = rx - rjb.x, dyb = ry - rjb.y, dzb = rz - rjb.z;
            float d2a = dxa*dxa + dya*dya + dza*dza;
            float d2b = dxb*dxb + dyb*dyb + dzb*dzb;
            // j==i: delta==0 exactly -> finite*0 == 0; clamp keeps rsq finite
            // at d2==0; for j!=i, d2 >> 1e-37 so bit-identical to rsq(d2).
            float inva = RSQ(fmaxf(d2a, 1e-37f));
            float invb = RSQ(fmaxf(d2b, 1e-37f));
            ax0 += inva * dxa; ay0 += inva * dya; az0 += inva * dza;
            ax1 += invb * dxb; ay1 += invb * dyb; az1 += invb * dzb;
        }

        float ax = ax0 + ax1, ay = ay0 + ay1, az = az0 + az1;
        float* dst = out + b * (NELEC * NDIM) + i * NDIM;  // 12B/lane, coalesced
        dst[0] = fmaf(wv, ax, rx);
        dst[1] = fmaf(wv, ay, ry);
        dst[2] = fmaf(wv, az, rz);
    }
}

extern "C" void kernel_launch(void* const* d_in, const int* in_sizes, int n_in,
                              void* d_out, int out_size, void* d_ws, size_t ws_size,
                              hipStream_t stream) {
    const float* pos = (const float*)d_in[0];
    const float* w   = (const float*)d_in[1];
    float* out       = (float*)d_out;
    const int B = in_sizes[0] / (NELEC * NDIM);
    const int grid = (B + BPB - 1) / BPB;
    backflow_kernel<<<dim3(grid), dim3(BLOCK), 0, stream>>>(pos, w, out, B);
}